// Round 10
// baseline (232.113 us; speedup 1.0000x reference)
//
#include <hip/hip_runtime.h>
#include <math.h>

// B=4096, IN=1024, H=2048, OUT=1024
// cosmic layer == broadcast prob[r] = (1/H)*(prod_{d,k} cos(cw[d,r,k]))^2
// Network = 6 fp16-MFMA GEMMs (16x16x32) with fused bias/relu/tanh epilogues.
//
// r10: G0-G4 use an m201-faithful 4-phase-per-K-tile schedule on a 256x128
// tile (grid 256 = full machine, 1 blk/CU, 8 waves 4Mx2N, per-wave 64x64):
// per phase {ds_read frags -> 2 stage glds -> barrier -> lgkmcnt(0) ->
// setprio -> 8 MFMA -> barrier}; vmcnt(6) once per tile (never drains).
// Tri-buffered 144 KB LDS. G5 keeps the r9 template (128x64, 2-3 blk/CU).
// XOR-swizzle both-sides (T2/rule 21), XCD swizzle (T1).

typedef _Float16 f16;
typedef _Float16 f16x8 __attribute__((ext_vector_type(8)));
typedef _Float16 f16x4 __attribute__((ext_vector_type(4)));
typedef float f32x4 __attribute__((ext_vector_type(4)));

#define GLD16(gp, lp) __builtin_amdgcn_global_load_lds( \
    (const __attribute__((address_space(1))) unsigned int*)(gp), \
    (__attribute__((address_space(3))) unsigned int*)(lp), 16, 0, 0)

__device__ __forceinline__ float tanh_fast(float x) {
  return 1.0f - 2.0f / (__expf(2.0f * x) + 1.0f);
}

// ---------------- fp32 -> fp16 cast ----------------
__global__ void cast_f32_f16(const float* __restrict__ in, f16* __restrict__ out, int n4) {
  int i = blockIdx.x * 256 + threadIdx.x;
  if (i < n4) {
    float4 v = ((const float4*)in)[i];
    f16x4 o = { (f16)v.x, (f16)v.y, (f16)v.z, (f16)v.w };
    ((f16x4*)out)[i] = o;
  }
}

// ------- merged cast+transpose, vectorized: 32(K) x 64(N) f32 tiles -------
struct TD { const float* src; f16* dst; int K; int N; };
struct TD6 { TD d[6]; };

__global__ void cast_transpose6(TD6 a) {
  TD d = a.d[blockIdx.z];
  const int bx = blockIdx.x * 64;   // N
  const int by = blockIdx.y * 32;   // K
  if (bx >= d.N || by >= d.K) return;
  __shared__ float tile[32][68];
  const int t = threadIdx.x;
#pragma unroll
  for (int pass = 0; pass < 2; ++pass) {
    int idx = t + pass * 256;
    int row = idx >> 4;
    int c4  = (idx & 15) * 4;
    float4 v = *(const float4*)&d.src[(size_t)(by + row) * d.N + bx + c4];
    *(float4*)&tile[row][c4] = v;
  }
  __syncthreads();
  const int nl = t >> 2;
  const int k8 = (t & 3) * 8;
  f16x8 o;
#pragma unroll
  for (int j = 0; j < 8; ++j) o[j] = (f16)tile[k8 + j][nl];
  *(f16x8*)&d.dst[(size_t)(bx + nl) * d.K + by + k8] = o;
}

// ---------------- cosmic prob, 2-pass, both tensors fused ----------------
__global__ void cosmic_pp2(const float* __restrict__ cw1, const float* __restrict__ cw2,
                           float* __restrict__ pp, int H) {
  int i = blockIdx.x * 256 + threadIdx.x;   // 0 .. 16H
  if (i >= 16 * H) return;
  const float* cw = (i < 8 * H) ? cw1 : cw2;
  int j = (i < 8 * H) ? i : i - 8 * H;
  const float* a = cw + (size_t)j * H;
  pp[i] = cosf(a[0]) * cosf(a[1]) * cosf(a[2]);
}
__global__ void cosmic_fin2(const float* __restrict__ pp, float* __restrict__ p1,
                            float* __restrict__ p2, int H) {
  int r = blockIdx.x * 256 + threadIdx.x;   // 0 .. 2H
  if (r >= 2 * H) return;
  int rr = (r < H) ? r : r - H;
  const float* base = pp + ((r < H) ? 0 : 8 * H);
  float p = 1.0f;
#pragma unroll
  for (int d = 0; d < 8; ++d) p *= base[d * H + rr];
  float v = p * p / (float)H;
  if (r < H) p1[rr] = v; else p2[rr] = v;
}

// ======== r10 main GEMM: 256x128, 4-phase/K-tile (m201 port) ========
// A: (M,K) f16 row-major. BT: (N,K) f16 row-major.
// EPI 0: relu->f16  1: tanh(+prob)->f16  2: relu->f32
template <int EPI>
__global__ __launch_bounds__(512, 2)
void gemm8(const f16* __restrict__ A, const f16* __restrict__ BT,
           const float* __restrict__ bias, const float* __restrict__ prob,
           f16* __restrict__ Ch, float* __restrict__ Cf,
           int M, int N, int K, int GX) {
  constexpr int BM = 256, BN = 128;
  constexpr int ASZ = BM * 64;          // 16384 f16
  constexpr int BSZ = BN * 64;          // 8192 f16
  __shared__ f16 lds[3 * (ASZ + BSZ)];  // 144 KB tri-buffer
  f16* As = lds;
  f16* Bs = lds + 3 * ASZ;

  const int t = threadIdx.x;

  // XCD-aware swizzle (nwg = 256)
  const int nwg = gridDim.x;
  const int bid = blockIdx.x;
  const int swz = (bid & 7) * (nwg >> 3) + (bid >> 3);
  const int bx = swz % GX;
  const int by = swz / GX;
  const int m0 = by * BM;
  const int n0 = bx * BN;

  // stage round q of tile kt into buf: q 0-3 = A (64 rows each), 4-5 = B.
  // LDS dest linear; XOR swizzle (chunk ^= row&7) on GLOBAL source (rule 21).
  auto stage = [&](int kt, int buf, int q) {
    const int k0 = kt << 6;
    if (q < 4) {
      int F = q * 4096 + t * 8;
      int r = F >> 6, c = (F >> 3) & 7;
      GLD16(A + (size_t)(m0 + r) * K + k0 + ((c ^ (r & 7)) << 3), As + buf * ASZ + F);
    } else {
      int F = (q - 4) * 4096 + t * 8;
      int r = F >> 6, c = (F >> 3) & 7;
      GLD16(BT + (size_t)(n0 + r) * K + k0 + ((c ^ (r & 7)) << 3), Bs + buf * BSZ + F);
    }
  };

  const int wave = t >> 6, lane = t & 63;
  const int wr = wave >> 1, wc = wave & 1;   // 4M x 2N waves; per-wave 64x64
  const int l16 = lane & 15, kq = lane >> 4;

  f32x4 acc[4][4] = {};
  f16x8 a[4], b[4];

  const int nt = K >> 6;
  // prologue: stage tiles 0 and 1 fully (12 glds in flight)
#pragma unroll
  for (int q = 0; q < 6; ++q) stage(0, 0, q);
#pragma unroll
  for (int q = 0; q < 6; ++q) stage(1, 1, q);
  asm volatile("s_waitcnt vmcnt(6)" ::: "memory");   // tile0 staged
  __builtin_amdgcn_s_barrier();

  int cur = 0;
  for (int kt = 0; kt < nt; ++kt) {
    int sb = cur + 2; if (sb >= 3) sb -= 3;
    const bool st = (kt + 2 < nt);
    const f16* Ab = As + cur * ASZ;
    const f16* Bb = Bs + cur * BSZ;

    // ---- 4 phases: (s,h) = (0,0),(0,1),(1,0),(1,1) ----
#pragma unroll
    for (int s = 0; s < 2; ++s) {
#pragma unroll
      for (int h = 0; h < 2; ++h) {
        const int cc = s * 4 + kq;
        // reads for THIS phase's MFMA burst
#pragma unroll
        for (int i = 0; i < 2; ++i) {
          int mr = h * 2 + i;
          int row = wr * 64 + mr * 16 + l16;
          a[mr] = *(const f16x8*)&Ab[row * 64 + ((cc ^ (row & 7)) << 3)];
        }
        if (h == 0) {
#pragma unroll
          for (int nr = 0; nr < 4; ++nr) {
            int row = wc * 64 + nr * 16 + l16;
            b[nr] = *(const f16x8*)&Bb[row * 64 + ((cc ^ (row & 7)) << 3)];
          }
        }
        // stage 2 glds for tile kt+2 on phases P1..P3
        const int ph = s * 2 + h;
        if (st && ph > 0) {
          stage(kt + 2, sb, (ph - 1) * 2);
          stage(kt + 2, sb, (ph - 1) * 2 + 1);
        }
        // vmcnt once per tile, at P3: tile kt+1's 6 retired, kt+2's in flight
        if (ph == 3) {
          if (kt + 2 < nt)      asm volatile("s_waitcnt vmcnt(6)" ::: "memory");
          else if (kt + 1 < nt) asm volatile("s_waitcnt vmcnt(0)" ::: "memory");
        }
        __builtin_amdgcn_s_barrier();
        asm volatile("s_waitcnt lgkmcnt(0)" ::: "memory");
        __builtin_amdgcn_sched_barrier(0);
        __builtin_amdgcn_s_setprio(1);
#pragma unroll
        for (int i = 0; i < 2; ++i)
#pragma unroll
          for (int nr = 0; nr < 4; ++nr)
            acc[h * 2 + i][nr] =
                __builtin_amdgcn_mfma_f32_16x16x32_f16(a[h * 2 + i], b[nr], acc[h * 2 + i][nr], 0, 0, 0);
        __builtin_amdgcn_s_setprio(0);
        __builtin_amdgcn_s_barrier();
      }
    }
    cur = (cur + 1 == 3) ? 0 : cur + 1;
  }

  // epilogue: 16x16 C/D layout col=lane&15, row=(lane>>4)*4+q
#pragma unroll
  for (int nr = 0; nr < 4; ++nr) {
    const int col = n0 + wc * 64 + nr * 16 + l16;
    float bn = bias[col];
    if (EPI == 1) bn += prob[col];
#pragma unroll
    for (int mr = 0; mr < 4; ++mr) {
      const int rbase = m0 + wr * 64 + mr * 16 + kq * 4;
#pragma unroll
      for (int q = 0; q < 4; ++q) {
        float v = acc[mr][nr][q] + bn;
        if (EPI == 1) v = tanh_fast(v);
        else v = fmaxf(v, 0.0f);
        if (EPI == 2) Cf[(size_t)(rbase + q) * N + col] = v;
        else Ch[(size_t)(rbase + q) * N + col] = (f16)v;
      }
    }
  }
}

// ======== r9 GEMM template (kept for G5: 128x64, 2-3 blk/CU) ========
template <int EPI, int BM, int BN, int MINW>
__global__ __launch_bounds__(256, MINW)
void gemm_f16(const f16* __restrict__ A, const f16* __restrict__ BT,
              const float* __restrict__ bias, const float* __restrict__ prob,
              f16* __restrict__ Ch, float* __restrict__ Cf,
              int M, int N, int K, int GX) {
  constexpr int ASZ = BM * 64;
  constexpr int BSZ = BN * 64;
  constexpr int MR  = BM / 32;
  constexpr int NR  = BN / 32;
  constexpr int RA  = ASZ / 2048;
  constexpr int RB  = BSZ / 2048;
  constexpr int NLD = RA + RB;
  __shared__ f16 lds[2 * (ASZ + BSZ)];
  f16* As = lds;
  f16* Bs = lds + 2 * ASZ;

  const int t = threadIdx.x;
  const int nwg = gridDim.x;
  const int bid = blockIdx.x;
  const int swz = (bid & 7) * (nwg >> 3) + (bid >> 3);
  const int bx = swz % GX;
  const int by = swz / GX;
  const int m0 = by * BM;
  const int n0 = bx * BN;

  auto stage_all = [&](int kt, int buf) {
    const int k0 = kt << 6;
#pragma unroll
    for (int q = 0; q < RA; ++q) {
      int F = q * 2048 + t * 8;
      int r = F >> 6, c = (F >> 3) & 7;
      GLD16(A + (size_t)(m0 + r) * K + k0 + ((c ^ (r & 7)) << 3), As + buf * ASZ + F);
    }
#pragma unroll
    for (int q = 0; q < RB; ++q) {
      int F = q * 2048 + t * 8;
      int r = F >> 6, c = (F >> 3) & 7;
      GLD16(BT + (size_t)(n0 + r) * K + k0 + ((c ^ (r & 7)) << 3), Bs + buf * BSZ + F);
    }
  };

  const int wave = t >> 6, lane = t & 63;
  const int wr = wave >> 1, wc = wave & 1;
  const int l16 = lane & 15, kq = lane >> 4;

  f32x4 acc[MR][NR] = {};

  const int nt = K >> 6;
  stage_all(0, 0);
  stage_all(1, 1);
  int cur = 0;
  for (int kt = 0; kt < nt; ++kt) {
    if (kt + 1 < nt) asm volatile("s_waitcnt vmcnt(%0)" :: "i"(NLD) : "memory");
    else             asm volatile("s_waitcnt vmcnt(0)" ::: "memory");
    __builtin_amdgcn_s_barrier();

    const f16* Ab = As + cur * ASZ;
    const f16* Bb = Bs + cur * BSZ;
    f16x8 a[2][MR], b[2][NR];
#pragma unroll
    for (int s = 0; s < 2; ++s) {
      const int cc = s * 4 + kq;
#pragma unroll
      for (int mr = 0; mr < MR; ++mr) {
        int row = wr * (MR * 16) + mr * 16 + l16;
        a[s][mr] = *(const f16x8*)&Ab[row * 64 + ((cc ^ (row & 7)) << 3)];
      }
#pragma unroll
      for (int nr = 0; nr < NR; ++nr) {
        int row = wc * (NR * 16) + nr * 16 + l16;
        b[s][nr] = *(const f16x8*)&Bb[row * 64 + ((cc ^ (row & 7)) << 3)];
      }
      __builtin_amdgcn_sched_barrier(0);
    }
    asm volatile("s_waitcnt lgkmcnt(%0)" :: "i"(MR + NR) : "memory");
    __builtin_amdgcn_sched_barrier(0);
    __builtin_amdgcn_s_setprio(1);
#pragma unroll
    for (int mr = 0; mr < MR; ++mr)
#pragma unroll
      for (int nr = 0; nr < NR; ++nr)
        acc[mr][nr] = __builtin_amdgcn_mfma_f32_16x16x32_f16(a[0][mr], b[0][nr], acc[mr][nr], 0, 0, 0);
    __builtin_amdgcn_s_setprio(0);
    asm volatile("s_waitcnt lgkmcnt(0)" ::: "memory");
    __builtin_amdgcn_sched_barrier(0);
    __builtin_amdgcn_s_barrier();
    if (kt + 2 < nt) stage_all(kt + 2, cur);
    __builtin_amdgcn_s_setprio(1);
#pragma unroll
    for (int mr = 0; mr < MR; ++mr)
#pragma unroll
      for (int nr = 0; nr < NR; ++nr)
        acc[mr][nr] = __builtin_amdgcn_mfma_f32_16x16x32_f16(a[1][mr], b[1][nr], acc[mr][nr], 0, 0, 0);
    __builtin_amdgcn_s_setprio(0);
    cur ^= 1;
  }

#pragma unroll
  for (int nr = 0; nr < NR; ++nr) {
    const int col = n0 + wc * (NR * 16) + nr * 16 + l16;
    float bn = bias[col];
    if (EPI == 1) bn += prob[col];
#pragma unroll
    for (int mr = 0; mr < MR; ++mr) {
      const int rbase = m0 + wr * (MR * 16) + mr * 16 + kq * 4;
#pragma unroll
      for (int q = 0; q < 4; ++q) {
        float v = acc[mr][nr][q] + bn;
        if (EPI == 1) v = tanh_fast(v);
        else v = fmaxf(v, 0.0f);
        if (EPI == 2) Cf[(size_t)(rbase + q) * N + col] = v;
        else Ch[(size_t)(rbase + q) * N + col] = (f16)v;
      }
    }
  }
}

extern "C" void kernel_launch(void* const* d_in, const int* in_sizes, int n_in,
                              void* d_out, int out_size, void* d_ws, size_t ws_size,
                              hipStream_t stream) {
  const float* x   = (const float*)d_in[0];
  const float* W0  = (const float*)d_in[1];
  const float* b0  = (const float*)d_in[2];
  const float* W1  = (const float*)d_in[3];
  const float* b1  = (const float*)d_in[4];
  const float* cw1 = (const float*)d_in[5];
  const float* KW1 = (const float*)d_in[7];
  const float* Kb1 = (const float*)d_in[8];
  const float* W2  = (const float*)d_in[9];
  const float* b2  = (const float*)d_in[10];
  const float* cw2 = (const float*)d_in[11];
  const float* KW2 = (const float*)d_in[13];
  const float* Kb2 = (const float*)d_in[14];
  const float* W3  = (const float*)d_in[15];
  const float* b3  = (const float*)d_in[16];

  const int B = 4096, IN = 1024, H = 2048, OUT = 1024;

  char* ws = (char*)d_ws;
  size_t off = 0;
  auto alloc = [&](size_t bytes) {
    char* p = ws + off;
    off = (off + bytes + 255) & ~(size_t)255;
    return p;
  };
  f16* xh    = (f16*)alloc((size_t)B * IN * 2);
  f16* W0T   = (f16*)alloc((size_t)H * IN * 2);
  f16* W1T   = (f16*)alloc((size_t)H * H * 2);
  f16* KW1T  = (f16*)alloc((size_t)H * H * 2);
  f16* W2T   = (f16*)alloc((size_t)H * H * 2);
  f16* KW2T  = (f16*)alloc((size_t)H * H * 2);
  f16* W3T   = (f16*)alloc((size_t)OUT * H * 2);
  f16* hA    = (f16*)alloc((size_t)B * H * 2);
  f16* hB    = (f16*)alloc((size_t)B * H * 2);
  float* p1  = (float*)alloc((size_t)H * 4);
  float* p2  = (float*)alloc((size_t)H * 4);
  float* pp  = (float*)alloc((size_t)16 * H * 4);
  (void)ws_size;

  cast_f32_f16<<<(B * IN / 4 + 255) / 256, 256, 0, stream>>>(x, xh, B * IN / 4);

  TD6 td;
  td.d[0] = { W0,  W0T,  IN, H };
  td.d[1] = { W1,  W1T,  H,  H };
  td.d[2] = { KW1, KW1T, H,  H };
  td.d[3] = { W2,  W2T,  H,  H };
  td.d[4] = { KW2, KW2T, H,  H };
  td.d[5] = { W3,  W3T,  H,  OUT };
  cast_transpose6<<<dim3(H / 64, H / 32, 6), 256, 0, stream>>>(td);

  cosmic_pp2<<<(16 * H + 255) / 256, 256, 0, stream>>>(cw1, cw2, pp, H);
  cosmic_fin2<<<(2 * H + 255) / 256, 256, 0, stream>>>(pp, p1, p2, H);

  // G0-G4: 256x128 4-phase kernel, grid 16x16=256 (1 blk/CU, 8 waves).
  {
    int gx = H / 128, gy = B / 256;
    dim3 g(gx * gy);
    gemm8<0><<<g, 512, 0, stream>>>(xh, W0T, b0,  nullptr, hA, nullptr, B, H, IN, gx);
    gemm8<0><<<g, 512, 0, stream>>>(hA, W1T, b1,  nullptr, hB, nullptr, B, H, H,  gx);
    gemm8<1><<<g, 512, 0, stream>>>(hB, KW1T, Kb1, p1,     hA, nullptr, B, H, H,  gx);
    gemm8<0><<<g, 512, 0, stream>>>(hA, W2T, b2,  nullptr, hB, nullptr, B, H, H,  gx);
    gemm8<1><<<g, 512, 0, stream>>>(hB, KW2T, Kb2, p2,     hA, nullptr, B, H, H,  gx);
  }
  // G5: r9 template, 128x64 tile, grid 16x32=512 -> 2-3 blocks/CU.
  {
    int gx = OUT / 64, gy = B / 128;
    dim3 g(gx * gy);
    gemm_f16<2, 128, 64, 3><<<g, 256, 0, stream>>>(hA, W3T, b3, nullptr, nullptr, (float*)d_out, B, OUT, H, gx);
  }
}